// Round 11
// baseline (223.927 us; speedup 1.0000x reference)
//
#include <hip/hip_runtime.h>
#include <stdint.h>
#include <math.h>

typedef __bf16 bf16;
typedef __bf16 bf16x4 __attribute__((ext_vector_type(4)));
typedef __bf16 bf16x8 __attribute__((ext_vector_type(8)));
typedef float floatx4 __attribute__((ext_vector_type(4)));
typedef float floatx16 __attribute__((ext_vector_type(16)));

#define CEXP 0.1803368801111204f  /* (1/8) * log2(e) */

typedef __attribute__((address_space(1))) const void gvoid_t;
typedef __attribute__((address_space(3))) void lvoid_t;
#define GLOAD_LDS16(g, l) \
  __builtin_amdgcn_global_load_lds((gvoid_t*)(g), (lvoid_t*)(l), 16, 0, 0)

// ---------------------------------------------------------------------------
// Merged pre-convert: fp32 -> bf16 with CHUNK SWIZZLE for the GEMM stage.
// Within every 64-col K-window, 16B chunk c of row r is stored at c ^ (r&7).
// (proven in round 10: qkv bank conflicts 9.5M -> 0, 55.7 -> <51.5 us)
// y = 0..3: Wq,Wk,Wv,Wo (1024x1024) -> Wb ; y = 4..6: q,k,v (4096x1024).
// ---------------------------------------------------------------------------
__global__ __launch_bounds__(256) void cvt_kernel(
    const float* __restrict__ Wq, const float* __restrict__ Wk,
    const float* __restrict__ Wv, const float* __restrict__ Wo,
    const float* __restrict__ q,  const float* __restrict__ k,
    const float* __restrict__ v,
    bf16* __restrict__ Wb, bf16* __restrict__ Qb,
    bf16* __restrict__ Kb, bf16* __restrict__ Vb)
{
  const int y = blockIdx.y;
  const float* src;
  bf16* dst;
  if (y < 4) {
    if (blockIdx.x >= 512) return;            // W: 1M elems = 512 blocks
    src = (y == 0) ? Wq : (y == 1) ? Wk : (y == 2) ? Wv : Wo;
    dst = Wb + (size_t)y * 1048576;
  } else {
    src = (y == 4) ? q : (y == 5) ? k : v;
    dst = (y == 4) ? Qb : (y == 5) ? Kb : Vb;
  }
  const int i   = blockIdx.x * 256 + threadIdx.x;  // 16B-chunk index
  const int row = i >> 7;                          // 128 chunks per 1024-col row
  const int cl  = i & 127;                         // chunk within row
  const int dc  = (cl & ~7) | ((cl ^ row) & 7);    // swizzled chunk position
  const floatx4 v0 = *(const floatx4*)(src + (size_t)i * 8);
  const floatx4 v1 = *(const floatx4*)(src + (size_t)i * 8 + 4);
  bf16x8 o;
#pragma unroll
  for (int j = 0; j < 4; ++j) { o[j] = (bf16)v0[j]; o[4 + j] = (bf16)v1[j]; }
  *(bf16x8*)(dst + (size_t)row * 1024 + dc * 8) = o;
}

// ---------------------------------------------------------------------------
// GEMM: C[M=128-tile, BN-tile] = A(bf16,chunk-swz) @ Wb(bf16,chunk-swz)^T
// + bias. m97 structure + de-swizzling ds_read (round-10 verified: 0 bank
// conflicts). BN parameter (128 or 64) sets the n-tile: BN=64 doubles the
// grid for out_kernel (1 block/CU -> 2, latency-bound regime fix).
// mode 0: C bf16 [b,h,s,dk] | mode 2 (BN=128 only): C bf16 [b,h,dk,s]
// mode 1: A gathered from Sb [b,h,s,dk] (chunk-swz by s&7); C fp32
// ---------------------------------------------------------------------------
__device__ __forceinline__ void gemm_body(
    const bf16* __restrict__ Ab,
    const bf16* __restrict__ Wb, const float* __restrict__ bias,
    void* __restrict__ Cout, const int mode, const float oscale, const int BN)
{
  // A 16K | B up to 16K = 32K pipeline; 36K epilogue scratch union (mode 2)
  __shared__ __align__(16) char smem[36864];

  const int tid  = threadIdx.x;
  const int wave = tid >> 6;
  const int lane = tid & 63;
  const int mlane = lane & 15;
  const int quad  = lane >> 4;
  const int m0 = blockIdx.x * 128;      // m-major grid
  const int n0 = blockIdx.y * BN;
  const int wm = (wave >> 1) * 64;
  const int wn = (wave & 1) * (BN >> 1);
  const int NT = BN >> 5;               // n-subtiles per wave (4 or 2)

  const int srow8 = tid >> 3;   // 0..31: row within 32-row group
  const int ch    = tid & 7;    // 16B chunk within the 128B row

  auto stage = [&](int k0) {
    bf16* Abuf = (bf16*)smem;
    bf16* Bbuf = (bf16*)(smem + 16384);
#pragma unroll
    for (int i = 0; i < 4; ++i) {
      const int row = i * 32 + srow8;
      const bf16* ga;
      if (mode == 1) {
        const int token = m0 + row;
        const int bb = token >> 11, s = token & 2047;
        const int h = k0 >> 6;  // BK=64 stays within one head
        ga = Ab + (((size_t)(bb * 16 + h) * 2048 + s) << 6) + ch * 8;
      } else {
        ga = Ab + (size_t)(m0 + row) * 1024 + k0 + ch * 8;
      }
      GLOAD_LDS16(ga, Abuf + i * 2048 + wave * 512);   // bytes: i*4096+w*1024
    }
#pragma unroll
    for (int i = 0; i < 4; ++i) {
      if (i >= (BN >> 5)) break;
      const int row = i * 32 + srow8;
      const bf16* gb = Wb + (size_t)(n0 + row) * 1024 + k0 + ch * 8;
      GLOAD_LDS16(gb, Bbuf + i * 2048 + wave * 512);
    }
  };

  floatx4 acc[4][4] = {};
  const int swz = mlane & 7;   // = row&7 for all fragment rows this lane reads

  for (int k0 = 0; k0 < 1024; k0 += 64) {
    stage(k0);
    __syncthreads();   // vmcnt(0)+barrier: tile resident

    const bf16* As = (const bf16*)smem;
    const bf16* Bs = (const bf16*)(smem + 16384);
#pragma unroll
    for (int kk = 0; kk < 64; kk += 32) {
      const int cidx = ((quad + (kk >> 3)) ^ swz) << 3;  // de-swizzled chunk
      bf16x8 af[4], bfr[4];
#pragma unroll
      for (int t = 0; t < 4; ++t)
        af[t] = *(const bf16x8*)&As[(wm + t * 16 + mlane) * 64 + cidx];
#pragma unroll
      for (int t = 0; t < 4; ++t) {
        if (t >= NT) break;
        bfr[t] = *(const bf16x8*)&Bs[(wn + t * 16 + mlane) * 64 + cidx];
      }
#pragma unroll
      for (int mt = 0; mt < 4; ++mt)
#pragma unroll
        for (int nt = 0; nt < 4; ++nt) {
          if (nt >= NT) break;
          acc[mt][nt] = __builtin_amdgcn_mfma_f32_16x16x32_bf16(
              af[mt], bfr[nt], acc[mt][nt], 0, 0, 0);
        }
    }
    __syncthreads();   // reads complete before next stage overwrites
  }

  // epilogue
  if (mode == 2) {
    // (BN=128 only) Transpose the wave's 64x64 tile through LDS scratch,
    // then 16B-coalesced stores.
    bf16* T = (bf16*)smem + wave * 4608;  // 64 rows x stride 72 = 9216B/wave
#pragma unroll
    for (int nt = 0; nt < 4; ++nt) {
      const float bv = bias[n0 + wn + nt * 16 + mlane];
#pragma unroll
      for (int mt = 0; mt < 4; ++mt) {
        bf16x4 t4;
#pragma unroll
        for (int r = 0; r < 4; ++r)
          t4[r] = (bf16)((acc[mt][nt][r] + bv) * oscale);
        *(bf16x4*)&T[(nt * 16 + mlane) * 72 + mt * 16 + quad * 4] = t4;
      }
    }
    asm volatile("s_waitcnt lgkmcnt(0)" ::: "memory");  // wave-local transpose
    const int token0 = m0 + wm;            // 64-aligned -> single b
    const int bb = token0 >> 11;
    const int srow0 = token0 & 2047;
    const int h = (n0 + wn) >> 6;          // 64-aligned -> single h
    const int dl = lane >> 3;
    const int s8 = (lane & 7) * 8;
    bf16* outp = (bf16*)Cout + ((size_t)(bb * 16 + h) << 17);
#pragma unroll
    for (int p = 0; p < 8; ++p) {
      const int dk = p * 8 + dl;
      const bf16x8 v8 = *(const bf16x8*)&T[dk * 72 + s8];
      *(bf16x8*)&outp[((size_t)dk << 11) + srow0 + s8] = v8;
    }
    return;
  }

#pragma unroll
  for (int nt = 0; nt < 4; ++nt) {
    if (nt >= NT) break;
    const int col = n0 + wn + nt * 16 + mlane;
    const float bv = bias[col];
#pragma unroll
    for (int mt = 0; mt < 4; ++mt) {
#pragma unroll
      for (int r = 0; r < 4; ++r) {
        const int row = m0 + wm + mt * 16 + quad * 4 + r;
        const float v = (acc[mt][nt][r] + bv) * oscale;
        if (mode == 0) {
          const int b = row >> 11, s = row & 2047;
          const int h = col >> 6, dk = col & 63;
          ((bf16*)Cout)[(((size_t)(b * 16 + h) * 2048 + s) << 6) + dk] = (bf16)v;
        } else {
          ((float*)Cout)[(size_t)row * 1024 + col] = v;
        }
      }
    }
  }
}

__global__ __launch_bounds__(256) void qkv_kernel(
    const bf16* __restrict__ Qb, const bf16* __restrict__ Kb,
    const bf16* __restrict__ Vb, const bf16* __restrict__ Wb,
    const float* __restrict__ bq, const float* __restrict__ bk,
    const float* __restrict__ bv,
    bf16* __restrict__ Qw, bf16* __restrict__ Kw, bf16* __restrict__ Vw)
{
  const int z = blockIdx.z;
  const bf16* A = (z == 0) ? Qb : (z == 1) ? Kb : Vb;
  const bf16* W = Wb + (size_t)z * 1048576;
  const float* B = (z == 0) ? bq : (z == 1) ? bk : bv;
  if (z == 2)      gemm_body(A, W, B, Vw, 2, 1.0f, 128);
  else if (z == 1) gemm_body(A, W, B, Kw, 0, 1.0f, 128);
  else             gemm_body(A, W, B, Qw, 0, CEXP, 128);
}

// 128x64 tiles -> 512 blocks = 2 blocks/CU (was 256 = 1/CU, latency-exposed)
__global__ __launch_bounds__(256) void out_kernel(
    const bf16* __restrict__ Sb, const bf16* __restrict__ Wob,
    const float* __restrict__ bo, float* __restrict__ out)
{
  gemm_body(Sb, Wob, bo, out, 1, 1.0f, 64);
}

// ---------------------------------------------------------------------------
// Flash attention, no-max softmax, 32x32x16 MFMA, P fully in-register.
// Round-11 change: 2-WAVE blocks of 64 q (was 4-wave / 128 q). Grid 512->1024
// -> 4 blocks/CU (same 8 waves/CU, but 4 independent 2-wave barrier groups
// instead of 2 heavyweight convoys). Round-10 counters showed MfmaUtil 26 /
// VALU 35 / LDS 39% with 0 conflicts: latency-bound, nothing saturated ->
// more independent streams is the mechanism-matched fix. K/V re-read 2x but
// L2-resident (4 heads x 512KB per XCD, swizzle-pinned).
// ---------------------------------------------------------------------------
__global__ __launch_bounds__(128, 2) void attn_kernel(
    const bf16* __restrict__ Qw, const bf16* __restrict__ Kw,
    const bf16* __restrict__ Vtg, float* __restrict__ scores,
    bf16* __restrict__ Sb)
{
  // 2 buffers x (Ks 64x136B | Vt 64x136B) = 34816 B
  __shared__ __align__(16) char smem[2 * 2 * 64 * 136];

  const int tid  = threadIdx.x;     // 0..127
  const int wave = tid >> 6;        // 0..1
  const int lane = tid & 63;
  const int c    = lane & 31;
  const int hi   = lane >> 5;

  // bijective XCD swizzle over 1024 blocks: XCD g%8 owns heads [4k,4k+4)
  const int g = blockIdx.x + (blockIdx.y << 5);
  const int slot = g >> 3;                  // 0..127
  const int bh = ((g & 7) << 2) + (slot >> 5);
  const int q0 = (slot & 31) << 6;          // 32 q-blocks of 64
  const size_t base = (size_t)bh << 17;     // bh * 2048 * 64

  const int srow = tid >> 1;                // staging: 64 rows, 2 thr/row
  const int sh   = (tid & 1) * 32;          // element offset (64B/thread)

  // loop-invariant Q B-frags: qf[m] -> Q[q0+wave*32+c][m*16+hi*8 ..+8]
  bf16x8 qf[4];
#pragma unroll
  for (int m = 0; m < 4; ++m)
    qf[m] = *(const bf16x8*)
        &Qw[base + (size_t)(q0 + wave * 32 + c) * 64 + m * 16 + hi * 8];

  floatx16 o[2] = {};          // [dk-half]; col=q=c, row=dk
  float rs = 0.f;

  bf16x8 kpf[4], vpf[4];
  auto load_kv = [&](int kt) {
    const bf16* kp = &Kw[base + (size_t)(kt + srow) * 64 + sh];
    const bf16* vp = &Vtg[base + (size_t)srow * 2048 + kt + sh];
#pragma unroll
    for (int j = 0; j < 4; ++j) {
      kpf[j] = *(const bf16x8*)(kp + j * 8);
      vpf[j] = *(const bf16x8*)(vp + j * 8);
    }
  };
  auto stage = [&](int b) {
    char* kr = smem + b * 17408 + srow * 136 + (tid & 1) * 64;
    char* vr = kr + 8704;
#pragma unroll
    for (int j = 0; j < 4; ++j) {
      *(bf16x4*)(kr + j * 16)     = ((const bf16x4*)&kpf[j])[0];
      *(bf16x4*)(kr + j * 16 + 8) = ((const bf16x4*)&kpf[j])[1];
      *(bf16x4*)(vr + j * 16)     = ((const bf16x4*)&vpf[j])[0];
      *(bf16x4*)(vr + j * 16 + 8) = ((const bf16x4*)&vpf[j])[1];
    }
  };

  load_kv(0);
  stage(0);
  load_kv(64);
  __syncthreads();

  for (int kt = 0; kt < 2048; kt += 64) {
    const int cur = (kt >> 6) & 1;
    if (kt + 64 < 2048) {
      stage(cur ^ 1);
      if (kt + 128 < 2048) load_kv(kt + 128);
    }
    const char* KsB = smem + cur * 17408;
    const char* VsB = KsB + 8704;

#pragma unroll
    for (int ks = 0; ks < 2; ++ks) {
      // S^T = K Q^T : A = K rows (keys ks*32+c), B = Q frags (reg)
      const char* krow = KsB + (ks * 32 + c) * 136;
      floatx16 s = {};
      __builtin_amdgcn_s_setprio(1);
#pragma unroll
      for (int m = 0; m < 4; ++m) {
        bf16x8 a;
        ((bf16x4*)&a)[0] = *(const bf16x4*)(krow + m * 32 + hi * 16);
        ((bf16x4*)&a)[1] = *(const bf16x4*)(krow + m * 32 + hi * 16 + 8);
        s = __builtin_amdgcn_mfma_f32_32x32x16_bf16(a, qf[m], s, 0, 0, 0);
      }
      __builtin_amdgcn_s_setprio(0);

      // raw-HW exp2 (compiler-visible builtin); reg i holds
      // key_local = 8*(i>>2) + (i&3) + 4*hi
      float p[16];
#pragma unroll
      for (int i = 0; i < 16; ++i) p[i] = __builtin_amdgcn_exp2f(s[i]);
#pragma unroll
      for (int i = 0; i < 16; ++i) rs += p[i];

      // pack: ulo[g] = keys 8g+4hi+{0,1}, uhi[g] = keys 8g+4hi+{2,3}
      uint32_t ulo[4], uhi[4];
#pragma unroll
      for (int gg = 0; gg < 4; ++gg) {
        asm("v_cvt_pk_bf16_f32 %0, %1, %2"
            : "=v"(ulo[gg]) : "v"(p[4 * gg]), "v"(p[4 * gg + 1]));
        asm("v_cvt_pk_bf16_f32 %0, %1, %2"
            : "=v"(uhi[gg]) : "v"(p[4 * gg + 2]), "v"(p[4 * gg + 3]));
      }

      // O^T += V^T P^T : B-frag(t) needs keys 16t+8hi+{0..7}; assemble via
      // permlane32_swap: {w0,w2} = swap(ulo[2t], ulo[2t+1]),
      //                  {w1,w3} = swap(uhi[2t], uhi[2t+1]).
      __builtin_amdgcn_s_setprio(1);
#pragma unroll
      for (int t = 0; t < 2; ++t) {
        uint32_t w0 = ulo[2 * t], w2 = ulo[2 * t + 1];
        uint32_t w1 = uhi[2 * t], w3 = uhi[2 * t + 1];
        asm("v_permlane32_swap_b32 %0, %1" : "+v"(w0), "+v"(w2));
        asm("v_permlane32_swap_b32 %0, %1" : "+v"(w1), "+v"(w3));
        union { bf16x8 v; uint32_t w[4]; } pu;
        pu.w[0] = w0; pu.w[1] = w1; pu.w[2] = w2; pu.w[3] = w3;
#pragma unroll
        for (int d = 0; d < 2; ++d) {
          const char* vrow = VsB + (d * 32 + c) * 136 + ks * 64 + t * 32 + hi * 16;
          bf16x8 va;
          ((bf16x4*)&va)[0] = *(const bf16x4*)(vrow);
          ((bf16x4*)&va)[1] = *(const bf16x4*)(vrow + 8);
          o[d] = __builtin_amdgcn_mfma_f32_32x32x16_bf16(va, pu.v, o[d], 0, 0, 0);
        }
      }
      __builtin_amdgcn_s_setprio(0);
    }
    __syncthreads();
  }

  // lanes (c,0)/(c,1) share q=c, hold complementary key subsets
  rs += __shfl_xor(rs, 32, 64);
  const float inv = 1.0f / rs;

  const int q = q0 + wave * 32 + c;
  const int ssw = c & 7;                    // = q&7 (q0,wave*32 mult of 8)
  float* sr = scores + base + (size_t)q * 64;
  bf16*  br = Sb + base + (size_t)q * 64;
#pragma unroll
  for (int d = 0; d < 2; ++d)
#pragma unroll
    for (int gg = 0; gg < 4; ++gg) {
      const int dk = d * 32 + gg * 8 + hi * 4;               // canonical
      const int dks = (((d * 4 + gg) ^ ssw) << 3) + hi * 4;  // swizzled (Sb)
      floatx4 v4;
      bf16x4 b4;
#pragma unroll
      for (int i = 0; i < 4; ++i) {
        const float v = o[d][gg * 4 + i] * inv;
        v4[i] = v;
        b4[i] = (bf16)v;
      }
      *(floatx4*)(sr + dk) = v4;
      *(bf16x4*)(br + dks) = b4;
    }
}

// ---------------------------------------------------------------------------
extern "C" void kernel_launch(void* const* d_in, const int* in_sizes, int n_in,
                              void* d_out, int out_size, void* d_ws, size_t ws_size,
                              hipStream_t stream) {
  const float* query = (const float*)d_in[0];
  const float* key   = (const float*)d_in[1];
  const float* value = (const float*)d_in[2];
  const float* Wq = (const float*)d_in[3];
  const float* bq = (const float*)d_in[4];
  const float* Wk = (const float*)d_in[5];
  const float* bk = (const float*)d_in[6];
  const float* Wv = (const float*)d_in[7];
  const float* bv = (const float*)d_in[8];
  const float* Wo = (const float*)d_in[9];
  const float* bo = (const float*)d_in[10];

  float* out    = (float*)d_out;
  float* scores = out + (size_t)4194304;   // second output (fp32)

  // workspace: Wb 8MB | Qws 8MB | Kws 8MB | Vws 8MB | Sb 8MB = 40 MB (proven)
  bf16* Wb  = (bf16*)d_ws;
  bf16* Qws = Wb  + (size_t)4194304;       // [b,h,s,dk], pre-scaled by CEXP
  bf16* Kws = Qws + (size_t)4194304;       // [b,h,s,dk]
  bf16* Vws = Kws + (size_t)4194304;       // [b,h,dk,s] (transposed)
  bf16* Sb  = Vws + (size_t)4194304;       // bf16 scores copy (chunk-swizzled)

  // bf16 input staging parked in the OUTPUT buffer (disjoint lifetimes):
  // Qb,Kb in `out` (written last, by out_kernel); Vb in `scores` (written
  // by attn_kernel, strictly after qkv_kernel consumed Vb).
  bf16* Qb = (bf16*)out;                   // 8 MB
  bf16* Kb = Qb + (size_t)4194304;         // 8 MB (second half of out)
  bf16* Vb = (bf16*)scores;                // 8 MB (first half of scores)

  cvt_kernel<<<dim3(2048, 7), 256, 0, stream>>>(Wq, Wk, Wv, Wo,
                                                query, key, value,
                                                Wb, Qb, Kb, Vb);
  qkv_kernel<<<dim3(32, 8, 3), 256, 0, stream>>>(Qb, Kb, Vb, Wb,
                                                 bq, bk, bv, Qws, Kws, Vws);
  attn_kernel<<<dim3(32, 32), 128, 0, stream>>>(Qws, Kws, Vws, scores, Sb);
  out_kernel<<<dim3(32, 16), 256, 0, stream>>>(Sb, Wb + (size_t)3145728, bo, out);
}

// Round 12
// 214.178 us; speedup vs baseline: 1.0455x; 1.0455x over previous
//
#include <hip/hip_runtime.h>
#include <stdint.h>
#include <math.h>

typedef __bf16 bf16;
typedef __bf16 bf16x4 __attribute__((ext_vector_type(4)));
typedef __bf16 bf16x8 __attribute__((ext_vector_type(8)));
typedef float floatx4 __attribute__((ext_vector_type(4)));
typedef float floatx16 __attribute__((ext_vector_type(16)));

#define CEXP 0.1803368801111204f  /* (1/8) * log2(e) */

typedef __attribute__((address_space(1))) const void gvoid_t;
typedef __attribute__((address_space(3))) void lvoid_t;
#define GLOAD_LDS16(g, l) \
  __builtin_amdgcn_global_load_lds((gvoid_t*)(g), (lvoid_t*)(l), 16, 0, 0)

// ---------------------------------------------------------------------------
// Merged pre-convert: fp32 -> bf16 with CHUNK SWIZZLE for the GEMM stage.
// Within every 64-col K-window, 16B chunk c of row r is stored at c ^ (r&7).
// (proven in round 10: qkv bank conflicts 9.5M -> 0)
// y = 0..3: Wq,Wk,Wv,Wo (1024x1024) -> Wb ; y = 4..6: q,k,v (4096x1024).
// ---------------------------------------------------------------------------
__global__ __launch_bounds__(256) void cvt_kernel(
    const float* __restrict__ Wq, const float* __restrict__ Wk,
    const float* __restrict__ Wv, const float* __restrict__ Wo,
    const float* __restrict__ q,  const float* __restrict__ k,
    const float* __restrict__ v,
    bf16* __restrict__ Wb, bf16* __restrict__ Qb,
    bf16* __restrict__ Kb, bf16* __restrict__ Vb)
{
  const int y = blockIdx.y;
  const float* src;
  bf16* dst;
  if (y < 4) {
    if (blockIdx.x >= 512) return;            // W: 1M elems = 512 blocks
    src = (y == 0) ? Wq : (y == 1) ? Wk : (y == 2) ? Wv : Wo;
    dst = Wb + (size_t)y * 1048576;
  } else {
    src = (y == 4) ? q : (y == 5) ? k : v;
    dst = (y == 4) ? Qb : (y == 5) ? Kb : Vb;
  }
  const int i   = blockIdx.x * 256 + threadIdx.x;  // 16B-chunk index
  const int row = i >> 7;                          // 128 chunks per 1024-col row
  const int cl  = i & 127;                         // chunk within row
  const int dc  = (cl & ~7) | ((cl ^ row) & 7);    // swizzled chunk position
  const floatx4 v0 = *(const floatx4*)(src + (size_t)i * 8);
  const floatx4 v1 = *(const floatx4*)(src + (size_t)i * 8 + 4);
  bf16x8 o;
#pragma unroll
  for (int j = 0; j < 4; ++j) { o[j] = (bf16)v0[j]; o[4 + j] = (bf16)v1[j]; }
  *(bf16x8*)(dst + (size_t)row * 1024 + dc * 8) = o;
}

// ---------------------------------------------------------------------------
// GEMM: C[M=128-tile, BN-tile] = A(bf16,chunk-swz) @ Wb(bf16,chunk-swz)^T
// + bias. m97 structure + de-swizzling ds_read (round-10 verified: 0 bank
// conflicts). BN=64 for out_kernel (2 blocks/CU; round-11 verified ~+4us).
// mode 0: C bf16 [b,h,s,dk] | mode 2 (BN=128 only): C bf16 [b,h,dk,s]
// mode 1: A gathered from Sb [b,h,s,dk] (chunk-swz by s&7); C fp32
// ---------------------------------------------------------------------------
__device__ __forceinline__ void gemm_body(
    const bf16* __restrict__ Ab,
    const bf16* __restrict__ Wb, const float* __restrict__ bias,
    void* __restrict__ Cout, const int mode, const float oscale, const int BN)
{
  // A 16K | B up to 16K = 32K pipeline; 36K epilogue scratch union (mode 2)
  __shared__ __align__(16) char smem[36864];

  const int tid  = threadIdx.x;
  const int wave = tid >> 6;
  const int lane = tid & 63;
  const int mlane = lane & 15;
  const int quad  = lane >> 4;
  const int m0 = blockIdx.x * 128;      // m-major grid
  const int n0 = blockIdx.y * BN;
  const int wm = (wave >> 1) * 64;
  const int wn = (wave & 1) * (BN >> 1);
  const int NT = BN >> 5;               // n-subtiles per wave (4 or 2)

  const int srow8 = tid >> 3;   // 0..31: row within 32-row group
  const int ch    = tid & 7;    // 16B chunk within the 128B row

  auto stage = [&](int k0) {
    bf16* Abuf = (bf16*)smem;
    bf16* Bbuf = (bf16*)(smem + 16384);
#pragma unroll
    for (int i = 0; i < 4; ++i) {
      const int row = i * 32 + srow8;
      const bf16* ga;
      if (mode == 1) {
        const int token = m0 + row;
        const int bb = token >> 11, s = token & 2047;
        const int h = k0 >> 6;  // BK=64 stays within one head
        ga = Ab + (((size_t)(bb * 16 + h) * 2048 + s) << 6) + ch * 8;
      } else {
        ga = Ab + (size_t)(m0 + row) * 1024 + k0 + ch * 8;
      }
      GLOAD_LDS16(ga, Abuf + i * 2048 + wave * 512);   // bytes: i*4096+w*1024
    }
#pragma unroll
    for (int i = 0; i < 4; ++i) {
      if (i >= (BN >> 5)) break;
      const int row = i * 32 + srow8;
      const bf16* gb = Wb + (size_t)(n0 + row) * 1024 + k0 + ch * 8;
      GLOAD_LDS16(gb, Bbuf + i * 2048 + wave * 512);
    }
  };

  floatx4 acc[4][4] = {};
  const int swz = mlane & 7;   // = row&7 for all fragment rows this lane reads

  for (int k0 = 0; k0 < 1024; k0 += 64) {
    stage(k0);
    __syncthreads();   // vmcnt(0)+barrier: tile resident

    const bf16* As = (const bf16*)smem;
    const bf16* Bs = (const bf16*)(smem + 16384);
#pragma unroll
    for (int kk = 0; kk < 64; kk += 32) {
      const int cidx = ((quad + (kk >> 3)) ^ swz) << 3;  // de-swizzled chunk
      bf16x8 af[4], bfr[4];
#pragma unroll
      for (int t = 0; t < 4; ++t)
        af[t] = *(const bf16x8*)&As[(wm + t * 16 + mlane) * 64 + cidx];
#pragma unroll
      for (int t = 0; t < 4; ++t) {
        if (t >= NT) break;
        bfr[t] = *(const bf16x8*)&Bs[(wn + t * 16 + mlane) * 64 + cidx];
      }
#pragma unroll
      for (int mt = 0; mt < 4; ++mt)
#pragma unroll
        for (int nt = 0; nt < 4; ++nt) {
          if (nt >= NT) break;
          acc[mt][nt] = __builtin_amdgcn_mfma_f32_16x16x32_bf16(
              af[mt], bfr[nt], acc[mt][nt], 0, 0, 0);
        }
    }
    __syncthreads();   // reads complete before next stage overwrites
  }

  // epilogue
  if (mode == 2) {
    // (BN=128 only) Transpose the wave's 64x64 tile through LDS scratch,
    // then 16B-coalesced stores.
    bf16* T = (bf16*)smem + wave * 4608;  // 64 rows x stride 72 = 9216B/wave
#pragma unroll
    for (int nt = 0; nt < 4; ++nt) {
      const float bv = bias[n0 + wn + nt * 16 + mlane];
#pragma unroll
      for (int mt = 0; mt < 4; ++mt) {
        bf16x4 t4;
#pragma unroll
        for (int r = 0; r < 4; ++r)
          t4[r] = (bf16)((acc[mt][nt][r] + bv) * oscale);
        *(bf16x4*)&T[(nt * 16 + mlane) * 72 + mt * 16 + quad * 4] = t4;
      }
    }
    asm volatile("s_waitcnt lgkmcnt(0)" ::: "memory");  // wave-local transpose
    const int token0 = m0 + wm;            // 64-aligned -> single b
    const int bb = token0 >> 11;
    const int srow0 = token0 & 2047;
    const int h = (n0 + wn) >> 6;          // 64-aligned -> single h
    const int dl = lane >> 3;
    const int s8 = (lane & 7) * 8;
    bf16* outp = (bf16*)Cout + ((size_t)(bb * 16 + h) << 17);
#pragma unroll
    for (int p = 0; p < 8; ++p) {
      const int dk = p * 8 + dl;
      const bf16x8 v8 = *(const bf16x8*)&T[dk * 72 + s8];
      *(bf16x8*)&outp[((size_t)dk << 11) + srow0 + s8] = v8;
    }
    return;
  }

#pragma unroll
  for (int nt = 0; nt < 4; ++nt) {
    if (nt >= NT) break;
    const int col = n0 + wn + nt * 16 + mlane;
    const float bv = bias[col];
#pragma unroll
    for (int mt = 0; mt < 4; ++mt) {
#pragma unroll
      for (int r = 0; r < 4; ++r) {
        const int row = m0 + wm + mt * 16 + quad * 4 + r;
        const float v = (acc[mt][nt][r] + bv) * oscale;
        if (mode == 0) {
          const int b = row >> 11, s = row & 2047;
          const int h = col >> 6, dk = col & 63;
          ((bf16*)Cout)[(((size_t)(b * 16 + h) * 2048 + s) << 6) + dk] = (bf16)v;
        } else {
          ((float*)Cout)[(size_t)row * 1024 + col] = v;
        }
      }
    }
  }
}

__global__ __launch_bounds__(256) void qkv_kernel(
    const bf16* __restrict__ Qb, const bf16* __restrict__ Kb,
    const bf16* __restrict__ Vb, const bf16* __restrict__ Wb,
    const float* __restrict__ bq, const float* __restrict__ bk,
    const float* __restrict__ bv,
    bf16* __restrict__ Qw, bf16* __restrict__ Kw, bf16* __restrict__ Vw)
{
  const int z = blockIdx.z;
  const bf16* A = (z == 0) ? Qb : (z == 1) ? Kb : Vb;
  const bf16* W = Wb + (size_t)z * 1048576;
  const float* B = (z == 0) ? bq : (z == 1) ? bk : bv;
  if (z == 2)      gemm_body(A, W, B, Vw, 2, 1.0f, 128);
  else if (z == 1) gemm_body(A, W, B, Kw, 0, 1.0f, 128);
  else             gemm_body(A, W, B, Qw, 0, CEXP, 128);
}

// 128x64 tiles -> 512 blocks = 2 blocks/CU (round-11 verified gain)
__global__ __launch_bounds__(256) void out_kernel(
    const bf16* __restrict__ Sb, const bf16* __restrict__ Wob,
    const float* __restrict__ bo, float* __restrict__ out)
{
  gemm_body(Sb, Wob, bo, out, 1, 1.0f, 64);
}

// ---------------------------------------------------------------------------
// Flash attention, no-max softmax, 32x32x16 MFMA, P fully in-register.
// Round-12: round-10 config (4 waves / 128 q / grid 512, 51.6us proven) with
// INTRA-TILE PHASE PIPELINING: issue BOTH half-tiles' QK chains first (two
// independent 4-MFMA chains), then exp/pack(s0)+PV(ks0), then exp/pack(s1)
// — which executes on the VALU while PV(ks0)'s MFMAs are still crunching —
// then PV(ks1). Round-11 showed the TLP axis is exhausted (2-wave blocks
// regressed); the serial QK->exp->pack->PV chain is the measured bottleneck
// (MfmaUtil 26 + VALUBusy 35, neither pipe saturated).
// ---------------------------------------------------------------------------
__global__ __launch_bounds__(256, 2) void attn_kernel(
    const bf16* __restrict__ Qw, const bf16* __restrict__ Kw,
    const bf16* __restrict__ Vtg, float* __restrict__ scores,
    bf16* __restrict__ Sb)
{
  // 2 buffers x (Ks 64x136B | Vt 64x136B) = 34816 B
  __shared__ __align__(16) char smem[2 * 2 * 64 * 136];

  const int tid  = threadIdx.x;
  const int wave = tid >> 6;
  const int lane = tid & 63;
  const int c    = lane & 31;
  const int hi   = lane >> 5;

  // bijective XCD swizzle over 512 blocks: XCD g%8 owns heads [4k,4k+4)
  const int g = blockIdx.x + (blockIdx.y << 4);
  const int slot = g >> 3;
  const int bh = ((g & 7) << 2) + (slot >> 4);
  const int q0 = (slot & 15) << 7;
  const size_t base = (size_t)bh << 17;            // bh * 2048 * 64

  const int srow = tid >> 2;                       // staging: 64 rows, 4 thr/row
  const int sce  = (tid & 3) * 16;                 // element col (32B/thread)

  // loop-invariant Q B-frags: qf[m] -> Q[q0+wave*32+c][m*16+hi*8 ..+8]
  bf16x8 qf[4];
#pragma unroll
  for (int m = 0; m < 4; ++m)
    qf[m] = *(const bf16x8*)
        &Qw[base + (size_t)(q0 + wave * 32 + c) * 64 + m * 16 + hi * 8];

  floatx16 o[2] = {};          // [dk-half]; col=q=c, row=dk
  float rs = 0.f;

  bf16x8 kpf[2], vpf[2];
  auto load_kv = [&](int kt) {
    const bf16* kp = &Kw[base + (size_t)(kt + srow) * 64 + sce];
    kpf[0] = *(const bf16x8*)kp;
    kpf[1] = *(const bf16x8*)(kp + 8);
    const bf16* vp = &Vtg[base + (size_t)srow * 2048 + kt + sce];
    vpf[0] = *(const bf16x8*)vp;
    vpf[1] = *(const bf16x8*)(vp + 8);
  };
  auto stage = [&](int b) {
    char* kr = smem + b * 17408 + srow * 136 + (tid & 3) * 32;
    char* vr = kr + 8704;
    *(bf16x4*)(kr +  0) = ((const bf16x4*)&kpf[0])[0];
    *(bf16x4*)(kr +  8) = ((const bf16x4*)&kpf[0])[1];
    *(bf16x4*)(kr + 16) = ((const bf16x4*)&kpf[1])[0];
    *(bf16x4*)(kr + 24) = ((const bf16x4*)&kpf[1])[1];
    *(bf16x4*)(vr +  0) = ((const bf16x4*)&vpf[0])[0];
    *(bf16x4*)(vr +  8) = ((const bf16x4*)&vpf[0])[1];
    *(bf16x4*)(vr + 16) = ((const bf16x4*)&vpf[1])[0];
    *(bf16x4*)(vr + 24) = ((const bf16x4*)&vpf[1])[1];
  };

  load_kv(0);
  stage(0);
  load_kv(64);
  __syncthreads();

  for (int kt = 0; kt < 2048; kt += 64) {
    const int cur = (kt >> 6) & 1;
    if (kt + 64 < 2048) {
      stage(cur ^ 1);
      if (kt + 128 < 2048) load_kv(kt + 128);
    }
    const char* KsB = smem + cur * 17408;
    const char* VsB = KsB + 8704;

    // ---- QK for BOTH half-tiles: two independent 4-MFMA chains ----
    floatx16 s0 = {}, s1 = {};
    {
      const char* krow0 = KsB + c * 136;
      const char* krow1 = KsB + (32 + c) * 136;
      __builtin_amdgcn_s_setprio(1);
#pragma unroll
      for (int m = 0; m < 4; ++m) {
        bf16x8 a0, a1;
        ((bf16x4*)&a0)[0] = *(const bf16x4*)(krow0 + m * 32 + hi * 16);
        ((bf16x4*)&a0)[1] = *(const bf16x4*)(krow0 + m * 32 + hi * 16 + 8);
        ((bf16x4*)&a1)[0] = *(const bf16x4*)(krow1 + m * 32 + hi * 16);
        ((bf16x4*)&a1)[1] = *(const bf16x4*)(krow1 + m * 32 + hi * 16 + 8);
        s0 = __builtin_amdgcn_mfma_f32_32x32x16_bf16(a0, qf[m], s0, 0, 0, 0);
        s1 = __builtin_amdgcn_mfma_f32_32x32x16_bf16(a1, qf[m], s1, 0, 0, 0);
      }
      __builtin_amdgcn_s_setprio(0);
    }

    // ---- exp/pack(s_ks) + PV(ks); exp(s1) overlaps PV(ks0) MFMAs ----
#pragma unroll
    for (int ks = 0; ks < 2; ++ks) {
      const floatx16& s = ks ? s1 : s0;
      // raw-HW exp2; reg i holds key_local = 8*(i>>2) + (i&3) + 4*hi
      float p[16];
#pragma unroll
      for (int i = 0; i < 16; ++i) p[i] = __builtin_amdgcn_exp2f(s[i]);
#pragma unroll
      for (int i = 0; i < 16; ++i) rs += p[i];

      // pack: ulo[g] = keys 8g+4hi+{0,1}, uhi[g] = keys 8g+4hi+{2,3}
      uint32_t ulo[4], uhi[4];
#pragma unroll
      for (int gg = 0; gg < 4; ++gg) {
        asm("v_cvt_pk_bf16_f32 %0, %1, %2"
            : "=v"(ulo[gg]) : "v"(p[4 * gg]), "v"(p[4 * gg + 1]));
        asm("v_cvt_pk_bf16_f32 %0, %1, %2"
            : "=v"(uhi[gg]) : "v"(p[4 * gg + 2]), "v"(p[4 * gg + 3]));
      }

      // O^T += V^T P^T : B-frag(t) needs keys 16t+8hi+{0..7}; assemble via
      // permlane32_swap: {w0,w2} = swap(ulo[2t], ulo[2t+1]),
      //                  {w1,w3} = swap(uhi[2t], uhi[2t+1]).
      __builtin_amdgcn_s_setprio(1);
#pragma unroll
      for (int t = 0; t < 2; ++t) {
        uint32_t w0 = ulo[2 * t], w2 = ulo[2 * t + 1];
        uint32_t w1 = uhi[2 * t], w3 = uhi[2 * t + 1];
        asm("v_permlane32_swap_b32 %0, %1" : "+v"(w0), "+v"(w2));
        asm("v_permlane32_swap_b32 %0, %1" : "+v"(w1), "+v"(w3));
        union { bf16x8 v; uint32_t w[4]; } pu;
        pu.w[0] = w0; pu.w[1] = w1; pu.w[2] = w2; pu.w[3] = w3;
#pragma unroll
        for (int d = 0; d < 2; ++d) {
          const char* vrow = VsB + (d * 32 + c) * 136 + ks * 64 + t * 32 + hi * 16;
          bf16x8 va;
          ((bf16x4*)&va)[0] = *(const bf16x4*)(vrow);
          ((bf16x4*)&va)[1] = *(const bf16x4*)(vrow + 8);
          o[d] = __builtin_amdgcn_mfma_f32_32x32x16_bf16(va, pu.v, o[d], 0, 0, 0);
        }
      }
      __builtin_amdgcn_s_setprio(0);
    }
    __syncthreads();
  }

  // lanes (c,0)/(c,1) share q=c, hold complementary key subsets
  rs += __shfl_xor(rs, 32, 64);
  const float inv = 1.0f / rs;

  const int q = q0 + wave * 32 + c;
  const int ssw = c & 7;                    // = q&7 (q0,wave*32 mult of 8)
  float* sr = scores + base + (size_t)q * 64;
  bf16*  br = Sb + base + (size_t)q * 64;
#pragma unroll
  for (int d = 0; d < 2; ++d)
#pragma unroll
    for (int gg = 0; gg < 4; ++gg) {
      const int dk = d * 32 + gg * 8 + hi * 4;               // canonical
      const int dks = (((d * 4 + gg) ^ ssw) << 3) + hi * 4;  // swizzled (Sb)
      floatx4 v4;
      bf16x4 b4;
#pragma unroll
      for (int i = 0; i < 4; ++i) {
        const float v = o[d][gg * 4 + i] * inv;
        v4[i] = v;
        b4[i] = (bf16)v;
      }
      *(floatx4*)(sr + dk) = v4;
      *(bf16x4*)(br + dks) = b4;
    }
}

// ---------------------------------------------------------------------------
extern "C" void kernel_launch(void* const* d_in, const int* in_sizes, int n_in,
                              void* d_out, int out_size, void* d_ws, size_t ws_size,
                              hipStream_t stream) {
  const float* query = (const float*)d_in[0];
  const float* key   = (const float*)d_in[1];
  const float* value = (const float*)d_in[2];
  const float* Wq = (const float*)d_in[3];
  const float* bq = (const float*)d_in[4];
  const float* Wk = (const float*)d_in[5];
  const float* bk = (const float*)d_in[6];
  const float* Wv = (const float*)d_in[7];
  const float* bv = (const float*)d_in[8];
  const float* Wo = (const float*)d_in[9];
  const float* bo = (const float*)d_in[10];

  float* out    = (float*)d_out;
  float* scores = out + (size_t)4194304;   // second output (fp32)

  // workspace: Wb 8MB | Qws 8MB | Kws 8MB | Vws 8MB | Sb 8MB = 40 MB (proven)
  bf16* Wb  = (bf16*)d_ws;
  bf16* Qws = Wb  + (size_t)4194304;       // [b,h,s,dk], pre-scaled by CEXP
  bf16* Kws = Qws + (size_t)4194304;       // [b,h,s,dk]
  bf16* Vws = Kws + (size_t)4194304;       // [b,h,dk,s] (transposed)
  bf16* Sb  = Vws + (size_t)4194304;       // bf16 scores copy (chunk-swizzled)

  // bf16 input staging parked in the OUTPUT buffer (disjoint lifetimes):
  // Qb,Kb in `out` (written last, by out_kernel); Vb in `scores` (written
  // by attn_kernel, strictly after qkv_kernel consumed Vb).
  bf16* Qb = (bf16*)out;                   // 8 MB
  bf16* Kb = Qb + (size_t)4194304;         // 8 MB (second half of out)
  bf16* Vb = (bf16*)scores;                // 8 MB (first half of scores)

  cvt_kernel<<<dim3(2048, 7), 256, 0, stream>>>(Wq, Wk, Wv, Wo,
                                                query, key, value,
                                                Wb, Qb, Kb, Vb);
  qkv_kernel<<<dim3(32, 8, 3), 256, 0, stream>>>(Qb, Kb, Vb, Wb,
                                                 bq, bk, bv, Qws, Kws, Vws);
  attn_kernel<<<dim3(16, 32), 256, 0, stream>>>(Qws, Kws, Vws, scores, Sb);
  out_kernel<<<dim3(32, 16), 256, 0, stream>>>(Sb, Wb + (size_t)3145728, bo, out);
}

// Round 13
// 209.908 us; speedup vs baseline: 1.0668x; 1.0203x over previous
//
#include <hip/hip_runtime.h>
#include <stdint.h>
#include <math.h>

typedef __bf16 bf16;
typedef __bf16 bf16x4 __attribute__((ext_vector_type(4)));
typedef __bf16 bf16x8 __attribute__((ext_vector_type(8)));
typedef float floatx4 __attribute__((ext_vector_type(4)));
typedef float floatx16 __attribute__((ext_vector_type(16)));

#define CEXP 0.1803368801111204f  /* (1/8) * log2(e) */

typedef __attribute__((address_space(1))) const void gvoid_t;
typedef __attribute__((address_space(3))) void lvoid_t;
#define GLOAD_LDS16(g, l) \
  __builtin_amdgcn_global_load_lds((gvoid_t*)(g), (lvoid_t*)(l), 16, 0, 0)

// ---------------------------------------------------------------------------
// Merged pre-convert: fp32 -> bf16 with CHUNK SWIZZLE for the GEMM stage.
// Within every 64-col K-window, 16B chunk c of row r is stored at c ^ (r&7).
// (proven in round 10: qkv bank conflicts 9.5M -> 0)
// y = 0..3: Wq,Wk,Wv,Wo (1024x1024) -> Wb ; y = 4..6: q,k,v (4096x1024).
// ---------------------------------------------------------------------------
__global__ __launch_bounds__(256) void cvt_kernel(
    const float* __restrict__ Wq, const float* __restrict__ Wk,
    const float* __restrict__ Wv, const float* __restrict__ Wo,
    const float* __restrict__ q,  const float* __restrict__ k,
    const float* __restrict__ v,
    bf16* __restrict__ Wb, bf16* __restrict__ Qb,
    bf16* __restrict__ Kb, bf16* __restrict__ Vb)
{
  const int y = blockIdx.y;
  const float* src;
  bf16* dst;
  if (y < 4) {
    if (blockIdx.x >= 512) return;            // W: 1M elems = 512 blocks
    src = (y == 0) ? Wq : (y == 1) ? Wk : (y == 2) ? Wv : Wo;
    dst = Wb + (size_t)y * 1048576;
  } else {
    src = (y == 4) ? q : (y == 5) ? k : v;
    dst = (y == 4) ? Qb : (y == 5) ? Kb : Vb;
  }
  const int i   = blockIdx.x * 256 + threadIdx.x;  // 16B-chunk index
  const int row = i >> 7;                          // 128 chunks per 1024-col row
  const int cl  = i & 127;                         // chunk within row
  const int dc  = (cl & ~7) | ((cl ^ row) & 7);    // swizzled chunk position
  const floatx4 v0 = *(const floatx4*)(src + (size_t)i * 8);
  const floatx4 v1 = *(const floatx4*)(src + (size_t)i * 8 + 4);
  bf16x8 o;
#pragma unroll
  for (int j = 0; j < 4; ++j) { o[j] = (bf16)v0[j]; o[4 + j] = (bf16)v1[j]; }
  *(bf16x8*)(dst + (size_t)row * 1024 + dc * 8) = o;
}

// ---------------------------------------------------------------------------
// GEMM: C[M=128-tile, BN-tile] = A(bf16,chunk-swz) @ Wb(bf16,chunk-swz)^T
// + bias. m97 structure + de-swizzling ds_read (round-10 verified: 0 bank
// conflicts). BN is a TEMPLATE param so the smem footprint shrinks with it:
// BN=64 -> 24.6KB LDS -> 4 blocks/CU resident (VGPR-capped) + block refill,
// vs BN=128's fixed 3/CU with none (round-12: qkv latency-bound, Occ 15.5%,
// all pipes <17%). Round-11 verified this same move on out_kernel.
// mode 0: C bf16 [b,h,s,dk] | mode 2: C bf16 [b,h,dk,s] via LDS transpose
// (generic over BN: dk0=(n0+wn)&63) | mode 1: A gathered from Sb (chunk-swz
// by s&7); C fp32 [token][col]
// ---------------------------------------------------------------------------
template <int BN>
__device__ __forceinline__ void gemm_body(
    const bf16* __restrict__ Ab,
    const bf16* __restrict__ Wb, const float* __restrict__ bias,
    void* __restrict__ Cout, const int mode, const float oscale)
{
  // A 16K | B BN*128B; mode-2 scratch (4 waves x BN/2 x 72 x 2B) fits both.
  __shared__ __align__(16) char smem[(BN == 128) ? 36864 : 24576];

  const int tid  = threadIdx.x;
  const int wave = tid >> 6;
  const int lane = tid & 63;
  const int mlane = lane & 15;
  const int quad  = lane >> 4;
  const int m0 = blockIdx.x * 128;      // m-major grid
  const int n0 = blockIdx.y * BN;
  const int wm = (wave >> 1) * 64;
  const int wn = (wave & 1) * (BN >> 1);
  const int NT = BN >> 5;               // n-subtiles per wave (4 or 2)

  const int srow8 = tid >> 3;   // 0..31: row within 32-row group
  const int ch    = tid & 7;    // 16B chunk within the 128B row

  // stage one 128x64 A-tile + BNx64 B-tile via global_load_lds (sources are
  // chunk-swizzled arrays loaded LINEARLY; de-swizzle happens on ds_read).
  // A/B issues interleaved (round-10 parity).
  auto stage = [&](int k0) {
    bf16* Abuf = (bf16*)smem;
    bf16* Bbuf = (bf16*)(smem + 16384);
#pragma unroll
    for (int i = 0; i < 4; ++i) {
      const int row = i * 32 + srow8;
      const bf16* ga;
      if (mode == 1) {
        const int token = m0 + row;
        const int bb = token >> 11, s = token & 2047;
        const int h = k0 >> 6;  // BK=64 stays within one head
        ga = Ab + (((size_t)(bb * 16 + h) * 2048 + s) << 6) + ch * 8;
      } else {
        ga = Ab + (size_t)(m0 + row) * 1024 + k0 + ch * 8;
      }
      GLOAD_LDS16(ga, Abuf + i * 2048 + wave * 512);   // bytes: i*4096+w*1024
      if (i < (BN >> 5)) {
        const bf16* gb = Wb + (size_t)(n0 + row) * 1024 + k0 + ch * 8;
        GLOAD_LDS16(gb, Bbuf + i * 2048 + wave * 512);
      }
    }
  };

  floatx4 acc[4][4] = {};
  const int swz = mlane & 7;   // = row&7 for all fragment rows this lane reads

  for (int k0 = 0; k0 < 1024; k0 += 64) {
    stage(k0);
    __syncthreads();   // vmcnt(0)+barrier: tile resident

    const bf16* As = (const bf16*)smem;
    const bf16* Bs = (const bf16*)(smem + 16384);
#pragma unroll
    for (int kk = 0; kk < 64; kk += 32) {
      const int cidx = ((quad + (kk >> 3)) ^ swz) << 3;  // de-swizzled chunk
      bf16x8 af[4], bfr[4];
#pragma unroll
      for (int t = 0; t < 4; ++t)
        af[t] = *(const bf16x8*)&As[(wm + t * 16 + mlane) * 64 + cidx];
#pragma unroll
      for (int t = 0; t < 4; ++t) {
        if (t >= NT) break;
        bfr[t] = *(const bf16x8*)&Bs[(wn + t * 16 + mlane) * 64 + cidx];
      }
#pragma unroll
      for (int mt = 0; mt < 4; ++mt)
#pragma unroll
        for (int nt = 0; nt < 4; ++nt) {
          if (nt >= NT) break;
          acc[mt][nt] = __builtin_amdgcn_mfma_f32_16x16x32_bf16(
              af[mt], bfr[nt], acc[mt][nt], 0, 0, 0);
        }
    }
    __syncthreads();   // reads complete before next stage overwrites
  }

  // epilogue
  if (mode == 2) {
    // Transpose the wave's 64m x (BN/2)n tile through LDS scratch (safe
    // after the loop's trailing barrier), then 16B-coalesced stores.
    const int HN = BN >> 1;               // wave n-extent (64 or 32)
    bf16* T = (bf16*)smem + wave * (HN * 72);
#pragma unroll
    for (int nt = 0; nt < 4; ++nt) {
      if (nt >= NT) break;
      const float bv = bias[n0 + wn + nt * 16 + mlane];
#pragma unroll
      for (int mt = 0; mt < 4; ++mt) {
        bf16x4 t4;
#pragma unroll
        for (int r = 0; r < 4; ++r)
          t4[r] = (bf16)((acc[mt][nt][r] + bv) * oscale);
        *(bf16x4*)&T[(nt * 16 + mlane) * 72 + mt * 16 + quad * 4] = t4;
      }
    }
    asm volatile("s_waitcnt lgkmcnt(0)" ::: "memory");  // wave-local transpose
    const int token0 = m0 + wm;            // 64-aligned -> single b
    const int bb = token0 >> 11;
    const int srow0 = token0 & 2047;
    const int h   = (n0 + wn) >> 6;        // single h (dk0 in {0,32})
    const int dk0 = (n0 + wn) & 63;
    const int dl = lane >> 3;
    const int s8 = (lane & 7) * 8;
    bf16* outp = (bf16*)Cout + ((size_t)(bb * 16 + h) << 17);
#pragma unroll
    for (int p = 0; p < 8; ++p) {
      if (p >= (BN >> 4)) break;           // BN/16 stores per lane
      const int dk = p * 8 + dl;           // 0..HN-1
      const bf16x8 v8 = *(const bf16x8*)&T[dk * 72 + s8];
      *(bf16x8*)&outp[((size_t)(dk0 + dk) << 11) + srow0 + s8] = v8;
    }
    return;
  }

#pragma unroll
  for (int nt = 0; nt < 4; ++nt) {
    if (nt >= NT) break;
    const int col = n0 + wn + nt * 16 + mlane;
    const float bv = bias[col];
#pragma unroll
    for (int mt = 0; mt < 4; ++mt) {
#pragma unroll
      for (int r = 0; r < 4; ++r) {
        const int row = m0 + wm + mt * 16 + quad * 4 + r;
        const float v = (acc[mt][nt][r] + bv) * oscale;
        if (mode == 0) {
          const int b = row >> 11, s = row & 2047;
          const int h = col >> 6, dk = col & 63;
          ((bf16*)Cout)[(((size_t)(b * 16 + h) * 2048 + s) << 6) + dk] = (bf16)v;
        } else {
          ((float*)Cout)[(size_t)row * 1024 + col] = v;
        }
      }
    }
  }
}

// BN=64: grid (32,16,3) = 1536 blocks -> 4 resident/CU + refill (was 3 fixed)
__global__ __launch_bounds__(256) void qkv_kernel(
    const bf16* __restrict__ Qb, const bf16* __restrict__ Kb,
    const bf16* __restrict__ Vb, const bf16* __restrict__ Wb,
    const float* __restrict__ bq, const float* __restrict__ bk,
    const float* __restrict__ bv,
    bf16* __restrict__ Qw, bf16* __restrict__ Kw, bf16* __restrict__ Vw)
{
  const int z = blockIdx.z;
  const bf16* A = (z == 0) ? Qb : (z == 1) ? Kb : Vb;
  const bf16* W = Wb + (size_t)z * 1048576;
  const float* B = (z == 0) ? bq : (z == 1) ? bk : bv;
  if (z == 2)      gemm_body<64>(A, W, B, Vw, 2, 1.0f);
  else if (z == 1) gemm_body<64>(A, W, B, Kw, 0, 1.0f);
  else             gemm_body<64>(A, W, B, Qw, 0, CEXP);
}

// 128x64 tiles -> 512 blocks = 2 blocks/CU (round-11 verified gain)
__global__ __launch_bounds__(256) void out_kernel(
    const bf16* __restrict__ Sb, const bf16* __restrict__ Wob,
    const float* __restrict__ bo, float* __restrict__ out)
{
  gemm_body<64>(Sb, Wob, bo, out, 1, 1.0f);
}

// ---------------------------------------------------------------------------
// Flash attention, no-max softmax, 32x32x16 MFMA, P fully in-register.
// Round-12 verified version (intra-tile phase pipelining: both QK chains
// first, exp/pack(s1) overlaps PV(ks0) MFMAs). Unchanged.
// ---------------------------------------------------------------------------
__global__ __launch_bounds__(256, 2) void attn_kernel(
    const bf16* __restrict__ Qw, const bf16* __restrict__ Kw,
    const bf16* __restrict__ Vtg, float* __restrict__ scores,
    bf16* __restrict__ Sb)
{
  // 2 buffers x (Ks 64x136B | Vt 64x136B) = 34816 B
  __shared__ __align__(16) char smem[2 * 2 * 64 * 136];

  const int tid  = threadIdx.x;
  const int wave = tid >> 6;
  const int lane = tid & 63;
  const int c    = lane & 31;
  const int hi   = lane >> 5;

  // bijective XCD swizzle over 512 blocks: XCD g%8 owns heads [4k,4k+4)
  const int g = blockIdx.x + (blockIdx.y << 4);
  const int slot = g >> 3;
  const int bh = ((g & 7) << 2) + (slot >> 4);
  const int q0 = (slot & 15) << 7;
  const size_t base = (size_t)bh << 17;            // bh * 2048 * 64

  const int srow = tid >> 2;                       // staging: 64 rows, 4 thr/row
  const int sce  = (tid & 3) * 16;                 // element col (32B/thread)

  // loop-invariant Q B-frags: qf[m] -> Q[q0+wave*32+c][m*16+hi*8 ..+8]
  bf16x8 qf[4];
#pragma unroll
  for (int m = 0; m < 4; ++m)
    qf[m] = *(const bf16x8*)
        &Qw[base + (size_t)(q0 + wave * 32 + c) * 64 + m * 16 + hi * 8];

  floatx16 o[2] = {};          // [dk-half]; col=q=c, row=dk
  float rs = 0.f;

  bf16x8 kpf[2], vpf[2];
  auto load_kv = [&](int kt) {
    const bf16* kp = &Kw[base + (size_t)(kt + srow) * 64 + sce];
    kpf[0] = *(const bf16x8*)kp;
    kpf[1] = *(const bf16x8*)(kp + 8);
    const bf16* vp = &Vtg[base + (size_t)srow * 2048 + kt + sce];
    vpf[0] = *(const bf16x8*)vp;
    vpf[1] = *(const bf16x8*)(vp + 8);
  };
  auto stage = [&](int b) {
    char* kr = smem + b * 17408 + srow * 136 + (tid & 3) * 32;
    char* vr = kr + 8704;
    *(bf16x4*)(kr +  0) = ((const bf16x4*)&kpf[0])[0];
    *(bf16x4*)(kr +  8) = ((const bf16x4*)&kpf[0])[1];
    *(bf16x4*)(kr + 16) = ((const bf16x4*)&kpf[1])[0];
    *(bf16x4*)(kr + 24) = ((const bf16x4*)&kpf[1])[1];
    *(bf16x4*)(vr +  0) = ((const bf16x4*)&vpf[0])[0];
    *(bf16x4*)(vr +  8) = ((const bf16x4*)&vpf[0])[1];
    *(bf16x4*)(vr + 16) = ((const bf16x4*)&vpf[1])[0];
    *(bf16x4*)(vr + 24) = ((const bf16x4*)&vpf[1])[1];
  };

  load_kv(0);
  stage(0);
  load_kv(64);
  __syncthreads();

  for (int kt = 0; kt < 2048; kt += 64) {
    const int cur = (kt >> 6) & 1;
    if (kt + 64 < 2048) {
      stage(cur ^ 1);
      if (kt + 128 < 2048) load_kv(kt + 128);
    }
    const char* KsB = smem + cur * 17408;
    const char* VsB = KsB + 8704;

    // ---- QK for BOTH half-tiles: two independent 4-MFMA chains ----
    floatx16 s0 = {}, s1 = {};
    {
      const char* krow0 = KsB + c * 136;
      const char* krow1 = KsB + (32 + c) * 136;
      __builtin_amdgcn_s_setprio(1);
#pragma unroll
      for (int m = 0; m < 4; ++m) {
        bf16x8 a0, a1;
        ((bf16x4*)&a0)[0] = *(const bf16x4*)(krow0 + m * 32 + hi * 16);
        ((bf16x4*)&a0)[1] = *(const bf16x4*)(krow0 + m * 32 + hi * 16 + 8);
        ((bf16x4*)&a1)[0] = *(const bf16x4*)(krow1 + m * 32 + hi * 16);
        ((bf16x4*)&a1)[1] = *(const bf16x4*)(krow1 + m * 32 + hi * 16 + 8);
        s0 = __builtin_amdgcn_mfma_f32_32x32x16_bf16(a0, qf[m], s0, 0, 0, 0);
        s1 = __builtin_amdgcn_mfma_f32_32x32x16_bf16(a1, qf[m], s1, 0, 0, 0);
      }
      __builtin_amdgcn_s_setprio(0);
    }

    // ---- exp/pack(s_ks) + PV(ks); exp(s1) overlaps PV(ks0) MFMAs ----
#pragma unroll
    for (int ks = 0; ks < 2; ++ks) {
      const floatx16& s = ks ? s1 : s0;
      // raw-HW exp2; reg i holds key_local = 8*(i>>2) + (i&3) + 4*hi
      float p[16];
#pragma unroll
      for (int i = 0; i < 16; ++i) p[i] = __builtin_amdgcn_exp2f(s[i]);
#pragma unroll
      for (int i = 0; i < 16; ++i) rs += p[i];

      // pack: ulo[g] = keys 8g+4hi+{0,1}, uhi[g] = keys 8g+4hi+{2,3}
      uint32_t ulo[4], uhi[4];
#pragma unroll
      for (int gg = 0; gg < 4; ++gg) {
        asm("v_cvt_pk_bf16_f32 %0, %1, %2"
            : "=v"(ulo[gg]) : "v"(p[4 * gg]), "v"(p[4 * gg + 1]));
        asm("v_cvt_pk_bf16_f32 %0, %1, %2"
            : "=v"(uhi[gg]) : "v"(p[4 * gg + 2]), "v"(p[4 * gg + 3]));
      }

      // O^T += V^T P^T : B-frag(t) needs keys 16t+8hi+{0..7}; assemble via
      // permlane32_swap: {w0,w2} = swap(ulo[2t], ulo[2t+1]),
      //                  {w1,w3} = swap(uhi[2t], uhi[2t+1]).
      __builtin_amdgcn_s_setprio(1);
#pragma unroll
      for (int t = 0; t < 2; ++t) {
        uint32_t w0 = ulo[2 * t], w2 = ulo[2 * t + 1];
        uint32_t w1 = uhi[2 * t], w3 = uhi[2 * t + 1];
        asm("v_permlane32_swap_b32 %0, %1" : "+v"(w0), "+v"(w2));
        asm("v_permlane32_swap_b32 %0, %1" : "+v"(w1), "+v"(w3));
        union { bf16x8 v; uint32_t w[4]; } pu;
        pu.w[0] = w0; pu.w[1] = w1; pu.w[2] = w2; pu.w[3] = w3;
#pragma unroll
        for (int d = 0; d < 2; ++d) {
          const char* vrow = VsB + (d * 32 + c) * 136 + ks * 64 + t * 32 + hi * 16;
          bf16x8 va;
          ((bf16x4*)&va)[0] = *(const bf16x4*)(vrow);
          ((bf16x4*)&va)[1] = *(const bf16x4*)(vrow + 8);
          o[d] = __builtin_amdgcn_mfma_f32_32x32x16_bf16(va, pu.v, o[d], 0, 0, 0);
        }
      }
      __builtin_amdgcn_s_setprio(0);
    }
    __syncthreads();
  }

  // lanes (c,0)/(c,1) share q=c, hold complementary key subsets
  rs += __shfl_xor(rs, 32, 64);
  const float inv = 1.0f / rs;

  const int q = q0 + wave * 32 + c;
  const int ssw = c & 7;                    // = q&7 (q0,wave*32 mult of 8)
  float* sr = scores + base + (size_t)q * 64;
  bf16*  br = Sb + base + (size_t)q * 64;
#pragma unroll
  for (int d = 0; d < 2; ++d)
#pragma unroll
    for (int gg = 0; gg < 4; ++gg) {
      const int dk = d * 32 + gg * 8 + hi * 4;               // canonical
      const int dks = (((d * 4 + gg) ^ ssw) << 3) + hi * 4;  // swizzled (Sb)
      floatx4 v4;
      bf16x4 b4;
#pragma unroll
      for (int i = 0; i < 4; ++i) {
        const float v = o[d][gg * 4 + i] * inv;
        v4[i] = v;
        b4[i] = (bf16)v;
      }
      *(floatx4*)(sr + dk) = v4;
      *(bf16x4*)(br + dks) = b4;
    }
}

// ---------------------------------------------------------------------------
extern "C" void kernel_launch(void* const* d_in, const int* in_sizes, int n_in,
                              void* d_out, int out_size, void* d_ws, size_t ws_size,
                              hipStream_t stream) {
  const float* query = (const float*)d_in[0];
  const float* key   = (const float*)d_in[1];
  const float* value = (const float*)d_in[2];
  const float* Wq = (const float*)d_in[3];
  const float* bq = (const float*)d_in[4];
  const float* Wk = (const float*)d_in[5];
  const float* bk = (const float*)d_in[6];
  const float* Wv = (const float*)d_in[7];
  const float* bv = (const float*)d_in[8];
  const float* Wo = (const float*)d_in[9];
  const float* bo = (const float*)d_in[10];

  float* out    = (float*)d_out;
  float* scores = out + (size_t)4194304;   // second output (fp32)

  // workspace: Wb 8MB | Qws 8MB | Kws 8MB | Vws 8MB | Sb 8MB = 40 MB (proven)
  bf16* Wb  = (bf16*)d_ws;
  bf16* Qws = Wb  + (size_t)4194304;       // [b,h,s,dk], pre-scaled by CEXP
  bf16* Kws = Qws + (size_t)4194304;       // [b,h,s,dk]
  bf16* Vws = Kws + (size_t)4194304;       // [b,h,dk,s] (transposed)
  bf16* Sb  = Vws + (size_t)4194304;       // bf16 scores copy (chunk-swizzled)

  // bf16 input staging parked in the OUTPUT buffer (disjoint lifetimes):
  // Qb,Kb in `out` (written last, by out_kernel); Vb in `scores` (written
  // by attn_kernel, strictly after qkv_kernel consumed Vb).
  bf16* Qb = (bf16*)out;                   // 8 MB
  bf16* Kb = Qb + (size_t)4194304;         // 8 MB (second half of out)
  bf16* Vb = (bf16*)scores;                // 8 MB (first half of scores)

  cvt_kernel<<<dim3(2048, 7), 256, 0, stream>>>(Wq, Wk, Wv, Wo,
                                                query, key, value,
                                                Wb, Qb, Kb, Vb);
  qkv_kernel<<<dim3(32, 16, 3), 256, 0, stream>>>(Qb, Kb, Vb, Wb,
                                                  bq, bk, bv, Qws, Kws, Vws);
  attn_kernel<<<dim3(16, 32), 256, 0, stream>>>(Qws, Kws, Vws, scores, Sb);
  out_kernel<<<dim3(32, 16), 256, 0, stream>>>(Sb, Wb + (size_t)3145728, bo, out);
}